// Round 10
// baseline (350.333 us; speedup 1.0000x reference)
//
#include <hip/hip_runtime.h>
#include <math.h>

// ---------------------------------------------------------------------------
// CenMoERewardModel. Round 10: ffn chunk loop re-ordered for latency hiding —
// BARX (no-vmcnt-drain barriers) + asm-pinned weight fragment loads so
// W2(c) hides under F-write+barrier+GEMM2-reads and W1(c+1) hides under
// GEMM2. Liveness kept <=~115 VGPR (no spills at the (512,2) 128-reg cap).
// attn / router / heads / combine unchanged from round 9.
// ---------------------------------------------------------------------------

typedef short bf16x8 __attribute__((ext_vector_type(8)));
typedef float f32x4 __attribute__((ext_vector_type(4)));
typedef unsigned short u16;

#define MFMA(a, b, c) __builtin_amdgcn_mfma_f32_16x16x32_bf16((a), (b), (c), 0, 0, 0)

// LDS-ordered barrier WITHOUT vmcnt(0) drain (T3/T4 analog; rule #18 guard).
#define BARX() do { \
    asm volatile("s_waitcnt lgkmcnt(0)" ::: "memory"); \
    __builtin_amdgcn_s_barrier(); \
    __builtin_amdgcn_sched_barrier(0); \
} while (0)

// keep a loaded fragment alive/issued at this program point (anti-sinking)
#define PIN(x) asm volatile("" :: "v"(x))

__device__ __forceinline__ u16 f2bf(float f) {
    unsigned int u = __float_as_uint(f);
    unsigned int r = u + 0x7FFFu + ((u >> 16) & 1u);
    return (u16)(r >> 16);
}
__device__ __forceinline__ float bf2f(u16 s) {
    return __uint_as_float(((unsigned int)s) << 16);
}

// ---------------- weight f32 -> bf16 conversion -----------------------------
__global__ __launch_bounds__(256) void convert_kernel(
    const float* __restrict__ wi, const float* __restrict__ wo,
    const float* __restrict__ w1, const float* __restrict__ w2,
    const float* __restrict__ hw1,
    u16* __restrict__ wiB, u16* __restrict__ woB, u16* __restrict__ w1B,
    u16* __restrict__ w2B, u16* __restrict__ hw1B)
{
    int i4 = blockIdx.x * 256 + threadIdx.x;  // 4608*256 = 1,179,648 exact
    int e = i4 * 4;
    const float* s; u16* d; int off;
    if (e < 393216)       { s = wi;  d = wiB;  off = e; }
    else if (e < 524288)  { s = wo;  d = woB;  off = e - 393216; }
    else if (e < 1572864) { s = w1;  d = w1B;  off = e - 524288; }
    else if (e < 2621440) { s = w2;  d = w2B;  off = e - 1572864; }
    else                  { s = hw1; d = hw1B; off = e - 2621440; }
    float4 v = *(const float4*)(s + off);
    ushort4 o;
    o.x = f2bf(v.x); o.y = f2bf(v.y); o.z = f2bf(v.z); o.w = f2bf(v.w);
    *(ushort4*)(d + off) = o;
}

// ---------------- Router (f32 exact) ---------------------------------------
__global__ __launch_bounds__(256) void router_kernel(
    const float* __restrict__ z, const float* __restrict__ a,
    const float* __restrict__ wg,
    float* __restrict__ gates_out, float* __restrict__ lse_ws,
    int* __restrict__ topi, float* __restrict__ topg)
{
    __shared__ float red[256][9];
    const int b = blockIdx.x, t = threadIdx.x;
    float acc[8];
#pragma unroll
    for (int e = 0; e < 8; ++e) acc[e] = 0.f;
#pragma unroll
    for (int i = 0; i < 16; ++i) {
        int f = i * 256 + t;
        int n = f >> 7, d = f & 127;
        float xv = (d < 96) ? z[(b * 32 + n) * 96 + d]
                            : a[(b * 32 + n) * 32 + d - 96];
        const float* wr = wg + f * 8;
#pragma unroll
        for (int e = 0; e < 8; ++e) acc[e] += xv * wr[e];
    }
#pragma unroll
    for (int e = 0; e < 8; ++e) red[t][e] = acc[e];
    __syncthreads();
    for (int s = 128; s; s >>= 1) {
        if (t < s) {
#pragma unroll
            for (int e = 0; e < 8; ++e) red[t][e] += red[t + s][e];
        }
        __syncthreads();
    }
    if (t == 0) {
        float L[8];
#pragma unroll
        for (int e = 0; e < 8; ++e) L[e] = red[0][e];
        int i0 = 0;
#pragma unroll
        for (int e = 1; e < 8; ++e) if (L[e] > L[i0]) i0 = e;
        int i1 = -1; float v1 = -3.0e38f;
#pragma unroll
        for (int e = 0; e < 8; ++e) if (e != i0 && L[e] > v1) { v1 = L[e]; i1 = e; }
        float e1 = expf(v1 - L[i0]);
        float inv = 1.f / (1.f + e1);
        float g0 = inv, g1 = e1 * inv;
#pragma unroll
        for (int e = 0; e < 8; ++e)
            gates_out[b * 8 + e] = (e == i0) ? g0 : ((e == i1) ? g1 : 0.f);
        float m = L[i0];
        float se = 0.f;
#pragma unroll
        for (int e = 0; e < 8; ++e) se += expf(L[e] - m);
        lse_ws[b] = m + logf(se);
        topi[b * 2 + 0] = i0; topi[b * 2 + 1] = i1;
        topg[b * 2 + 0] = g0; topg[b * 2 + 1] = g1;
    }
}

// ---------------- Build entry lists + pair/quad tilings + balance loss ------
__global__ __launch_bounds__(1024) void build_loss_kernel(
    const int* __restrict__ topi, const float* __restrict__ topg,
    const float* __restrict__ lse,
    int* __restrict__ cnts, int* __restrict__ ent, int* __restrict__ meta,
    int* __restrict__ metaF, float* __restrict__ out_loss)
{
    __shared__ int sc_[8];
    __shared__ int toff[8];
    __shared__ int toffF[8];
    __shared__ float red[9][1024];
    const int t = threadIdx.x;
    if (t < 8) sc_[t] = 0;
    __syncthreads();
    int e0 = topi[t * 2], e1 = topi[t * 2 + 1];
    float g0 = topg[t * 2], g1 = topg[t * 2 + 1];
    int p0 = atomicAdd(&sc_[e0], 1);
    ent[e0 * 2048 + p0] = t * 2;
    int p1 = atomicAdd(&sc_[e1], 1);
    ent[e1 * 2048 + p1] = t * 2 + 1;
#pragma unroll
    for (int e = 0; e < 8; ++e)
        red[e][t] = ((e == e0) ? g0 : 0.f) + ((e == e1) ? g1 : 0.f);
    red[8][t] = lse[t];
    __syncthreads();
    for (int s = 512; s; s >>= 1) {
        if (t < s) {
#pragma unroll
            for (int q = 0; q < 9; ++q) red[q][t] += red[q][t + s];
        }
        __syncthreads();
    }
    if (t == 0) {
        int off = 0, offF = 0;
        for (int e = 0; e < 8; ++e) {
            toff[e] = off;   off  += (sc_[e] + 1) >> 1;
            toffF[e] = offF; offF += (sc_[e] + 3) >> 2;
        }
        meta[0] = off;
        metaF[0] = offF;
        float cvv[2];
        for (int p = 0; p < 2; ++p) {
            float v[8], sum = 0.f;
            for (int e = 0; e < 8; ++e) {
                v[e] = p ? (float)sc_[e] : red[e][0];
                sum += v[e];
            }
            float mean = sum * (1.f / 8.f);
            float var = 0.f;
            for (int e = 0; e < 8; ++e) { float d = v[e] - mean; var += d * d; }
            var *= (1.f / 7.f);
            cvv[p] = var / (mean * mean + 1e-10f);
        }
        out_loss[0] = cvv[0] + cvv[1] + red[8][0] * (1.f / 1024.f);
    }
    __syncthreads();
    if (t < 8) {
        cnts[t] = sc_[t];
        int ntl = (sc_[t] + 1) >> 1, o = toff[t];
        for (int j = 0; j < ntl; ++j) {
            meta[1 + 2 * (o + j)] = t;
            meta[2 + 2 * (o + j)] = j * 2;
        }
        int ntlF = (sc_[t] + 3) >> 2, oF = toffF[t];
        for (int j = 0; j < ntlF; ++j) {
            metaF[1 + 2 * (oF + j)] = t;
            metaF[2 + 2 * (oF + j)] = j * 4;
        }
    }
}

// ---------------- Attn kernel: M=64, through LN1, writes h1 -----------------
#define SM_X 0
#define SM_Q 16384
#define SM_K 32768
#define SM_V 49152
#define SM_TOT 65536
#define PS_OFF 0
#define PQ_OFF 1024
#define MU_OFF 2048
#define RS_OFF 2304
#define NTILES 1028

__device__ __forceinline__ int tsw(int row, int col) {   // 256B-row bf16 tile
    return row * 256 + ((col * 2) ^ ((row & 7) << 4));
}
__device__ __forceinline__ int vsw(int row, int col) {   // 128B-row bf16 tile
    return row * 128 + ((col * 2) ^ ((row & 7) << 4));
}

__global__ __launch_bounds__(512, 2) void attn_kernel(
    const float* __restrict__ z, const float* __restrict__ a,
    const u16* __restrict__ wiBF, const float* __restrict__ b_in,
    const u16* __restrict__ woBF, const float* __restrict__ b_out,
    const float* __restrict__ ln1g, const float* __restrict__ ln1b,
    const int* __restrict__ cnts, const int* __restrict__ meta,
    const int* __restrict__ ent,
    u16* __restrict__ h1g)   // [2048 codes][32][128] bf16
{
    __shared__ __align__(16) char sm[SM_TOT];
    const int n_tiles = meta[0];
    const int bid = blockIdx.x;
    if (bid >= n_tiles) return;
    const int e = meta[1 + 2 * bid], base = meta[2 + 2 * bid];
    const int cnt = cnts[e];

    const int t = threadIdx.x;
    const int w = t >> 6, l = t & 63, l16 = l & 15, lk = l >> 4;
    const int ke = lk * 8;
    const int wr = w >> 2, wc = w & 3;   // 2M x 4N wave grid
    const f32x4 zv = {0.f, 0.f, 0.f, 0.f};

    int bs[2];
#pragma unroll
    for (int i = 0; i < 2; ++i) {
        int gi = base + i;
        int idx = (gi < cnt) ? gi : (cnt - 1);
        bs[i] = ent[e * 2048 + idx];
    }

    // ---- stage X = concat(z,a), bf16 swizzled
#pragma unroll
    for (int i = 0; i < 2; ++i) {
        int cid = i * 512 + t;
        int row = cid >> 4;             // 0..63
        int cb = (cid & 15) * 8;        // 0..120
        int b_ = bs[row >> 5] >> 1;
        int n = row & 31;
        float4 p0, p1;
        if (cb < 96) {
            const float* zp = z + ((size_t)b_ * 32 + n) * 96 + cb;
            p0 = *(const float4*)zp; p1 = *(const float4*)(zp + 4);
        } else {
            const float* ap = a + ((size_t)b_ * 32 + n) * 32 + (cb - 96);
            p0 = *(const float4*)ap; p1 = *(const float4*)(ap + 4);
        }
        bf16x8 pk;
        pk[0] = (short)f2bf(p0.x); pk[1] = (short)f2bf(p0.y);
        pk[2] = (short)f2bf(p0.z); pk[3] = (short)f2bf(p0.w);
        pk[4] = (short)f2bf(p1.x); pk[5] = (short)f2bf(p1.y);
        pk[6] = (short)f2bf(p1.z); pk[7] = (short)f2bf(p1.w);
        *(bf16x8*)(sm + SM_X + tsw(row, cb)) = pk;
    }
    __syncthreads();

    // ---- Phase 1: qkv GEMM  M=64 N=384 K=128
    {
        f32x4 acc[2][6];
#pragma unroll
        for (int mt = 0; mt < 2; ++mt)
#pragma unroll
            for (int q = 0; q < 6; ++q) acc[mt][q] = zv;
#pragma unroll
        for (int ks = 0; ks < 4; ++ks) {
            bf16x8 af[2];
#pragma unroll
            for (int mt = 0; mt < 2; ++mt) {
                int R = wr * 32 + mt * 16 + l16;
                af[mt] = *(const bf16x8*)(sm + SM_X + tsw(R, ks * 32 + ke));
            }
#pragma unroll
            for (int q = 0; q < 6; ++q) {
                int j = wc * 96 + q * 16 + l16;
                bf16x8 bb = *(const bf16x8*)(wiBF + e * 49152 + j * 128 + ks * 32 + ke);
#pragma unroll
                for (int mt = 0; mt < 2; ++mt) acc[mt][q] = MFMA(af[mt], bb, acc[mt][q]);
            }
        }
#pragma unroll
        for (int q = 0; q < 6; ++q) {
            int C = wc * 96 + q * 16 + l16;
            float bj = b_in[e * 384 + C];
#pragma unroll
            for (int mt = 0; mt < 2; ++mt)
#pragma unroll
                for (int i = 0; i < 4; ++i) {
                    int R = wr * 32 + mt * 16 + lk * 4 + i;
                    u16 val = f2bf(acc[mt][q][i] + bj);
                    if (C < 128) {
                        *(u16*)(sm + SM_Q + tsw(R, C)) = val;
                    } else if (C < 256) {
                        *(u16*)(sm + SM_K + tsw(R, C - 128)) = val;
                    } else {
                        *(u16*)(sm + SM_V + vsw(C - 256, R)) = val;  // VT[d][key]
                    }
                }
        }
    }
    __syncthreads();

    // ---- Phase 2: attention; wave w -> (tok = w>>2, head = w&3)
    {
        const int tok = w >> 2, hb = (w & 3) * 32;
        const float scale = 0.17677669529663687f;  // 1/sqrt(32)
        bf16x8 qa[2], kf[2];
#pragma unroll
        for (int mt = 0; mt < 2; ++mt) {
            int R = tok * 32 + mt * 16 + l16;
            qa[mt] = *(const bf16x8*)(sm + SM_Q + tsw(R, hb + ke));
            kf[mt] = *(const bf16x8*)(sm + SM_K + tsw(R, hb + ke));
        }
        f32x4 sc[2][2];
        sc[0][0] = MFMA(qa[0], kf[0], zv); sc[0][1] = MFMA(qa[0], kf[1], zv);
        sc[1][0] = MFMA(qa[1], kf[0], zv); sc[1][1] = MFMA(qa[1], kf[1], zv);
#pragma unroll
        for (int mt = 0; mt < 2; ++mt)
#pragma unroll
            for (int i = 0; i < 4; ++i) {
                float v0 = sc[mt][0][i] * scale, v1 = sc[mt][1][i] * scale;
                float m = fmaxf(v0, v1);
                m = fmaxf(m, __shfl_xor(m, 1)); m = fmaxf(m, __shfl_xor(m, 2));
                m = fmaxf(m, __shfl_xor(m, 4)); m = fmaxf(m, __shfl_xor(m, 8));
                float e0 = __expf(v0 - m), e1 = __expf(v1 - m);
                float ssum = e0 + e1;
                ssum += __shfl_xor(ssum, 1); ssum += __shfl_xor(ssum, 2);
                ssum += __shfl_xor(ssum, 4); ssum += __shfl_xor(ssum, 8);
                float inv = 1.f / ssum;
                int row = mt * 16 + lk * 4 + i;
                char* pb = sm + SM_X + w * 2048 + row * 64;
                int sw = (row & 3) << 4;
                *(u16*)(pb + ((l16 * 2) ^ sw)) = f2bf(e0 * inv);
                *(u16*)(pb + (((16 + l16) * 2) ^ sw)) = f2bf(e1 * inv);
            }
        bf16x8 pa[2];
#pragma unroll
        for (int mt = 0; mt < 2; ++mt) {
            int row = mt * 16 + l16;
            pa[mt] = *(const bf16x8*)(sm + SM_X + w * 2048 + row * 64 +
                                      ((ke * 2) ^ ((row & 3) << 4)));
        }
        f32x4 o[2][2];
#pragma unroll
        for (int nt = 0; nt < 2; ++nt) {
            int rv = hb + nt * 16 + l16;  // VT row = v column
            bf16x8 vb = *(const bf16x8*)(sm + SM_V + vsw(rv, tok * 32 + ke));
            o[0][nt] = MFMA(pa[0], vb, zv);
            o[1][nt] = MFMA(pa[1], vb, zv);
        }
#pragma unroll
        for (int mt = 0; mt < 2; ++mt)
#pragma unroll
            for (int nt = 0; nt < 2; ++nt)
#pragma unroll
                for (int i = 0; i < 4; ++i) {
                    int R = tok * 32 + mt * 16 + lk * 4 + i;
                    int C = hb + nt * 16 + l16;
                    *(u16*)(sm + SM_Q + tsw(R, C)) = f2bf(o[mt][nt][i]);
                }
    }
    __syncthreads();

    // ---- Phase 3: proj GEMM + residual(global f32) + LN1 stats
    {
        f32x4 pr[2][2];
        pr[0][0] = zv; pr[0][1] = zv; pr[1][0] = zv; pr[1][1] = zv;
#pragma unroll
        for (int ks = 0; ks < 4; ++ks) {
            bf16x8 af[2];
#pragma unroll
            for (int mt = 0; mt < 2; ++mt) {
                int R = wr * 32 + mt * 16 + l16;
                af[mt] = *(const bf16x8*)(sm + SM_Q + tsw(R, ks * 32 + ke));
            }
#pragma unroll
            for (int nt = 0; nt < 2; ++nt) {
                int j = wc * 32 + nt * 16 + l16;
                bf16x8 bb = *(const bf16x8*)(woBF + e * 16384 + j * 128 + ks * 32 + ke);
                pr[0][nt] = MFMA(af[0], bb, pr[0][nt]);
                pr[1][nt] = MFMA(af[1], bb, pr[1][nt]);
            }
        }
        int C0 = wc * 32 + l16, C1 = C0 + 16;
        float bo0 = b_out[e * 128 + C0];
        float bo1 = b_out[e * 128 + C1];
        int b_ = bs[wr] >> 1;
#pragma unroll
        for (int mt = 0; mt < 2; ++mt)
#pragma unroll
            for (int i = 0; i < 4; ++i) {
                int R = wr * 32 + mt * 16 + lk * 4 + i;
                int n = R & 31;
                float x0 = (C0 < 96) ? z[((size_t)b_ * 32 + n) * 96 + C0]
                                     : a[((size_t)b_ * 32 + n) * 32 + C0 - 96];
                float x1 = (C1 < 96) ? z[((size_t)b_ * 32 + n) * 96 + C1]
                                     : a[((size_t)b_ * 32 + n) * 32 + C1 - 96];
                float u0 = pr[mt][0][i] + bo0 + x0;
                float u1v = pr[mt][1][i] + bo1 + x1;
                *(u16*)(sm + SM_K + tsw(R, C0)) = f2bf(u0);
                *(u16*)(sm + SM_K + tsw(R, C1)) = f2bf(u1v);
                float s = u0 + u1v;
                float q = u0 * u0 + u1v * u1v;
                s += __shfl_xor(s, 1); q += __shfl_xor(q, 1);
                s += __shfl_xor(s, 2); q += __shfl_xor(q, 2);
                s += __shfl_xor(s, 4); q += __shfl_xor(q, 4);
                s += __shfl_xor(s, 8); q += __shfl_xor(q, 8);
                if (l16 == 0) {
                    *(float*)(sm + SM_X + PS_OFF + (R * 4 + wc) * 4) = s;
                    *(float*)(sm + SM_X + PQ_OFF + (R * 4 + wc) * 4) = q;
                }
            }
    }
    __syncthreads();
    if (t < 64) {
        float s = 0.f, q = 0.f;
#pragma unroll
        for (int c = 0; c < 4; ++c) {
            s += *(const float*)(sm + SM_X + PS_OFF + (t * 4 + c) * 4);
            q += *(const float*)(sm + SM_X + PQ_OFF + (t * 4 + c) * 4);
        }
        float mu = s * (1.f / 128.f);
        float var = q * (1.f / 128.f) - mu * mu;
        *(float*)(sm + SM_X + MU_OFF + t * 4) = mu;
        *(float*)(sm + SM_X + RS_OFF + t * 4) = rsqrtf(var + 1e-5f);
    }
    __syncthreads();
    {   // LN1 apply in place over SM_K
        int r_ = t >> 3, c0 = (t & 7) * 16;
        float mu_ = *(const float*)(sm + SM_X + MU_OFF + r_ * 4);
        float rs_ = *(const float*)(sm + SM_X + RS_OFF + r_ * 4);
#pragma unroll
        for (int j4 = 0; j4 < 2; ++j4) {
            int cb = c0 + j4 * 8;
            bf16x8* p = (bf16x8*)(sm + SM_K + tsw(r_, cb));
            bf16x8 vch = *p;
#pragma unroll
            for (int jj = 0; jj < 8; ++jj) {
                int c = cb + jj;
                float f = (bf2f((u16)vch[jj]) - mu_) * rs_ * ln1g[e * 128 + c] + ln1b[e * 128 + c];
                vch[jj] = (short)f2bf(f);
            }
            *p = vch;
        }
    }
    __syncthreads();
    // ---- write h1 to global (duplicate entries write identical bytes: benign)
#pragma unroll
    for (int i = 0; i < 2; ++i) {
        int cid = i * 512 + t;
        int r_ = cid >> 4, cb = (cid & 15) * 8;
        int code = bs[r_ >> 5];
        u16* dst = h1g + (size_t)code * 4096 + (r_ & 31) * 128 + cb;
        *(bf16x8*)dst = *(const bf16x8*)(sm + SM_K + tsw(r_, cb));
    }
}

// ---------------- FFN kernel: M=128 grouped GEMM, pipelined weights ---------
// LDS: H [128][128] bf16 swz @0 (32KB); F [128][128] @32768 (32KB);
// stats @65536. 2 blocks/CU. Waves: 2M x 4N.
// Chunk order: GEMM1 -> W2(c) issue+pin -> BARX -> F-write -> W1(c+1)
// issue+pin -> BARX -> GEMM2. Non-draining barriers keep loads in flight.
#define FH 0
#define FF 32768
#define FPS 65536
#define FPQ 67584
#define FMU 69632
#define FRS 70144
#define F_TOT 70656
#define NF_TILES 520

__global__ __launch_bounds__(512, 2) void ffn_kernel(
    const u16* __restrict__ h1g,
    const u16* __restrict__ w1BF, const float* __restrict__ b1,
    const u16* __restrict__ w2BF, const float* __restrict__ b2,
    const float* __restrict__ ln2g, const float* __restrict__ ln2b,
    const float* __restrict__ topg, const int* __restrict__ cnts,
    const int* __restrict__ metaF, const int* __restrict__ ent,
    u16* __restrict__ ybf)   // [2][1024][4096]
{
    __shared__ __align__(16) char sm[F_TOT];
    const int nf = metaF[0];
    const int bid = blockIdx.x;
    if (bid >= nf) return;
    const int e = metaF[1 + 2 * bid], base = metaF[2 + 2 * bid];
    const int cnt = cnts[e];

    const int t = threadIdx.x;
    const int w = t >> 6, l = t & 63, l16 = l & 15, lk = l >> 4;
    const int ke = lk * 8;
    const int wr = w >> 2, wc = w & 3;   // 2M x 4N
    const f32x4 zv = {0.f, 0.f, 0.f, 0.f};

    int code4[4]; float gg4[4];
#pragma unroll
    for (int i = 0; i < 4; ++i) {
        int gi = base + i;
        int idx = (gi < cnt) ? gi : (cnt - 1);
        code4[i] = ent[e * 2048 + idx];
        gg4[i] = topg[code4[i]];
    }

    // ---- stage H (LN1 output) from global: 128 rows x 128 cols
#pragma unroll
    for (int it = 0; it < 4; ++it) {
        int cid = it * 512 + t;
        int row = cid >> 4, cb = (cid & 15) * 8;
        int code = code4[row >> 5];
        *(bf16x8*)(sm + FH + tsw(row, cb)) =
            *(const bf16x8*)(h1g + (size_t)code * 4096 + (row & 31) * 128 + cb);
    }
    BARX();

    f32x4 facc[4][2];
#pragma unroll
    for (int mt = 0; mt < 4; ++mt) { facc[mt][0] = zv; facc[mt][1] = zv; }

    // W1 frags for chunk 0
    bf16x8 w1f[2][4];
#pragma unroll
    for (int nt = 0; nt < 2; ++nt)
#pragma unroll
        for (int ks = 0; ks < 4; ++ks) {
            int j = wc * 32 + nt * 16 + l16;
            w1f[nt][ks] = *(const bf16x8*)(w1BF + e * 131072 + j * 128 + ks * 32 + ke);
        }

    for (int c = 0; c < 8; ++c) {
        // GEMM1: a1 = H @ W1_chunk^T  (M=128 N=128 K=128; 32 MFMA/wave)
        f32x4 a1[4][2];
#pragma unroll
        for (int mt = 0; mt < 4; ++mt) { a1[mt][0] = zv; a1[mt][1] = zv; }
#pragma unroll
        for (int ks = 0; ks < 4; ++ks) {
            bf16x8 af[4];
#pragma unroll
            for (int mt = 0; mt < 4; ++mt) {
                int R = wr * 64 + mt * 16 + l16;
                af[mt] = *(const bf16x8*)(sm + FH + tsw(R, ks * 32 + ke));
            }
#pragma unroll
            for (int nt = 0; nt < 2; ++nt)
#pragma unroll
                for (int mt = 0; mt < 4; ++mt)
                    a1[mt][nt] = MFMA(af[mt], w1f[nt][ks], a1[mt][nt]);
        }
        // issue W2(c) now; pin so loads aren't sunk into GEMM2.
        // Window hides under F-write + barriers + GEMM2's ds_reads.
        bf16x8 w2f[2][4];
#pragma unroll
        for (int nt = 0; nt < 2; ++nt)
#pragma unroll
            for (int ks = 0; ks < 4; ++ks) {
                int j = wc * 32 + nt * 16 + l16;
                w2f[nt][ks] = *(const bf16x8*)(w2BF + e * 131072 + j * 1024 +
                                               c * 128 + ks * 32 + ke);
            }
#pragma unroll
        for (int nt = 0; nt < 2; ++nt)
#pragma unroll
            for (int ks = 0; ks < 4; ++ks) PIN(w2f[nt][ks]);

        BARX();   // prev chunk's F reads (GEMM2) complete; no vmcnt drain
#pragma unroll
        for (int nt = 0; nt < 2; ++nt) {
            int C = wc * 32 + nt * 16 + l16;
            float bv = b1[e * 1024 + c * 128 + C];
#pragma unroll
            for (int mt = 0; mt < 4; ++mt)
#pragma unroll
                for (int i = 0; i < 4; ++i) {
                    int R = wr * 64 + mt * 16 + lk * 4 + i;
                    *(u16*)(sm + FF + tsw(R, C)) = f2bf(fmaxf(a1[mt][nt][i] + bv, 0.f));
                }
        }
        // issue W1(c+1); pin before the barrier so the loads fly during GEMM2
        if (c < 7) {
#pragma unroll
            for (int nt = 0; nt < 2; ++nt)
#pragma unroll
                for (int ks = 0; ks < 4; ++ks) {
                    int j = (c + 1) * 128 + wc * 32 + nt * 16 + l16;
                    w1f[nt][ks] = *(const bf16x8*)(w1BF + e * 131072 + j * 128 + ks * 32 + ke);
                }
#pragma unroll
            for (int nt = 0; nt < 2; ++nt)
#pragma unroll
                for (int ks = 0; ks < 4; ++ks) PIN(w1f[nt][ks]);
        }
        BARX();   // F ready; W1(c+1) stays in flight
        // GEMM2: facc += F @ W2_chunk^T  (32 MFMA/wave)
#pragma unroll
        for (int ks = 0; ks < 4; ++ks) {
            bf16x8 af[4];
#pragma unroll
            for (int mt = 0; mt < 4; ++mt) {
                int R = wr * 64 + mt * 16 + l16;
                af[mt] = *(const bf16x8*)(sm + FF + tsw(R, ks * 32 + ke));
            }
#pragma unroll
            for (int nt = 0; nt < 2; ++nt)
#pragma unroll
                for (int mt = 0; mt < 4; ++mt)
                    facc[mt][nt] = MFMA(af[mt], w2f[nt][ks], facc[mt][nt]);
        }
    }
    BARX();   // last GEMM2's F reads done before u2 overwrites F

    // ---- epilogue: u2 = h1 + facc + b2 -> F (bf16); per-row partial stats
    {
        int C0 = wc * 32 + l16, C1 = C0 + 16;
        float b20 = b2[e * 128 + C0];
        float b21 = b2[e * 128 + C1];
#pragma unroll
        for (int mt = 0; mt < 4; ++mt)
#pragma unroll
            for (int i = 0; i < 4; ++i) {
                int R = wr * 64 + mt * 16 + lk * 4 + i;
                float h0 = bf2f(*(const u16*)(sm + FH + tsw(R, C0)));
                float h1v = bf2f(*(const u16*)(sm + FH + tsw(R, C1)));
                float u0 = facc[mt][0][i] + b20 + h0;
                float u1v = facc[mt][1][i] + b21 + h1v;
                *(u16*)(sm + FF + tsw(R, C0)) = f2bf(u0);
                *(u16*)(sm + FF + tsw(R, C1)) = f2bf(u1v);
                float s = u0 + u1v;
                float q = u0 * u0 + u1v * u1v;
                s += __shfl_xor(s, 1); q += __shfl_xor(q, 1);
                s += __shfl_xor(s, 2); q += __shfl_xor(q, 2);
                s += __shfl_xor(s, 4); q += __shfl_xor(q, 4);
                s += __shfl_xor(s, 8); q += __shfl_xor(q, 8);
                if (l16 == 0) {
                    *(float*)(sm + FPS + (R * 4 + wc) * 4) = s;
                    *(float*)(sm + FPQ + (R * 4 + wc) * 4) = q;
                }
            }
    }
    __syncthreads();
    if (t < 128) {
        float s = 0.f, q = 0.f;
#pragma unroll
        for (int c = 0; c < 4; ++c) {
            s += *(const float*)(sm + FPS + (t * 4 + c) * 4);
            q += *(const float*)(sm + FPQ + (t * 4 + c) * 4);
        }
        float mu = s * (1.f / 128.f);
        float var = q * (1.f / 128.f) - mu * mu;
        *(float*)(sm + FMU + t * 4) = mu;
        *(float*)(sm + FRS + t * 4) = rsqrtf(var + 1e-5f);
    }
    __syncthreads();
    // ---- LN2 apply + gate + write (duplicates write identical bytes)
#pragma unroll
    for (int it = 0; it < 4; ++it) {
        int cid = it * 512 + t;
        int row = cid >> 4, cb = (cid & 15) * 8;
        float mu = *(const float*)(sm + FMU + row * 4);
        float rs = *(const float*)(sm + FRS + row * 4);
        int ei = row >> 5;
        float gm = gg4[ei];
        int code = code4[ei];
        int tok = code >> 1, slot = code & 1;
        bf16x8 v = *(const bf16x8*)(sm + FF + tsw(row, cb));
        bf16x8 o;
#pragma unroll
        for (int jj = 0; jj < 8; ++jj) {
            int cc = cb + jj;
            float f = (bf2f((u16)v[jj]) - mu) * rs * ln2g[e * 128 + cc] + ln2b[e * 128 + cc];
            o[jj] = (short)f2bf(gm * f);
        }
        *(bf16x8*)(ybf + (size_t)(slot * 1024 + tok) * 4096 + (row & 31) * 128 + cb) = o;
    }
}

// ---------------- Combine: y = slot0 + slot1 (into slot0) ------------------
__global__ __launch_bounds__(256) void combine_kernel(
    u16* __restrict__ y0, const u16* __restrict__ y1)
{
    int i = (blockIdx.x * 256 + threadIdx.x) * 8;
    bf16x8 a = *(const bf16x8*)(y0 + i);
    bf16x8 b = *(const bf16x8*)(y1 + i);
    bf16x8 o;
#pragma unroll
    for (int j = 0; j < 8; ++j)
        o[j] = (short)f2bf(bf2f((u16)a[j]) + bf2f((u16)b[j]));
    *(bf16x8*)(y0 + i) = o;
}

// ---------------- Head1: h_act = relu(y @ hw1^T + hb1), bf16 MFMA -----------
__global__ __launch_bounds__(256) void head1_mfma(
    const u16* __restrict__ y_bf, const u16* __restrict__ hw1BF,
    const float* __restrict__ hb1, float* __restrict__ h_act)
{
    const int t = threadIdx.x, w = t >> 6, l = t & 63, l16 = l & 15, lk = l >> 4;
    const int ke = lk * 8;
    const int mb = blockIdx.x * 32, cb = blockIdx.y * 64 + w * 16;
    const f32x4 zv = {0.f, 0.f, 0.f, 0.f};
    f32x4 acc[2]; acc[0] = zv; acc[1] = zv;
    const u16* arow0 = y_bf + (size_t)(mb + l16) * 4096;
    const u16* arow1 = y_bf + (size_t)(mb + 16 + l16) * 4096;
    const u16* brow  = hw1BF + (size_t)(cb + l16) * 4096;
    for (int k0 = 0; k0 < 4096; k0 += 32) {
        bf16x8 a0 = *(const bf16x8*)(arow0 + k0 + ke);
        bf16x8 a1 = *(const bf16x8*)(arow1 + k0 + ke);
        bf16x8 bb = *(const bf16x8*)(brow + k0 + ke);
        acc[0] = MFMA(a0, bb, acc[0]);
        acc[1] = MFMA(a1, bb, acc[1]);
    }
    int col = cb + l16;
    float bv = hb1[col];
#pragma unroll
    for (int mt = 0; mt < 2; ++mt)
#pragma unroll
        for (int i = 0; i < 4; ++i) {
            int row = mb + mt * 16 + lk * 4 + i;
            h_act[(size_t)row * 512 + col] = fmaxf(acc[mt][i] + bv, 0.f);
        }
}

// ---------------- Head2 -----------------------------------------------------
__global__ __launch_bounds__(64) void head2_kernel(
    const float* __restrict__ h_act, const float* __restrict__ w2,
    const float* __restrict__ b2, float* __restrict__ r)
{
    const int b = blockIdx.x, t = threadIdx.x;
    float a0 = 0.f, a1 = 0.f, a2 = 0.f, a3 = 0.f;
    for (int h = t; h < 512; h += 64) {
        float hv = h_act[b * 512 + h];
        a0 += hv * w2[h];
        a1 += hv * w2[512 + h];
        a2 += hv * w2[1024 + h];
        a3 += hv * w2[1536 + h];
    }
#pragma unroll
    for (int off = 32; off; off >>= 1) {
        a0 += __shfl_down(a0, off);
        a1 += __shfl_down(a1, off);
        a2 += __shfl_down(a2, off);
        a3 += __shfl_down(a3, off);
    }
    if (t == 0) {
        r[b * 4 + 0] = a0 + b2[0];
        r[b * 4 + 1] = a1 + b2[1];
        r[b * 4 + 2] = a2 + b2[2];
        r[b * 4 + 3] = a3 + b2[3];
    }
}

// ---------------------------------------------------------------------------
extern "C" void kernel_launch(void* const* d_in, const int* in_sizes, int n_in,
                              void* d_out, int out_size, void* d_ws, size_t ws_size,
                              hipStream_t stream) {
    const float* z    = (const float*)d_in[0];
    const float* a    = (const float*)d_in[1];
    const float* wg   = (const float*)d_in[2];
    const float* w_in = (const float*)d_in[3];
    const float* b_in = (const float*)d_in[4];
    const float* w_o  = (const float*)d_in[5];
    const float* b_o  = (const float*)d_in[6];
    const float* l1g  = (const float*)d_in[7];
    const float* l1b  = (const float*)d_in[8];
    const float* w1   = (const float*)d_in[9];
    const float* b1   = (const float*)d_in[10];
    const float* w2   = (const float*)d_in[11];
    const float* b2   = (const float*)d_in[12];
    const float* l2g  = (const float*)d_in[13];
    const float* l2b  = (const float*)d_in[14];
    const float* hw1  = (const float*)d_in[15];
    const float* hb1  = (const float*)d_in[16];
    const float* hw2  = (const float*)d_in[17];
    const float* hb2  = (const float*)d_in[18];

    float* out = (float*)d_out;
    float* r_out     = out;          // 4096
    float* gates_out = out + 4096;   // 8192
    float* loss_out  = out + 12288;  // 1

    char* W = (char*)d_ws;
    u16*   wiBF  = (u16*)(W + 0);           //   786,432 B
    u16*   woBF  = (u16*)(W + 786432);      //   262,144 B
    u16*   w1BF  = (u16*)(W + 1048576);     // 2,097,152 B
    u16*   w2BF  = (u16*)(W + 3145728);     // 2,097,152 B
    u16*   hw1BF = (u16*)(W + 5242880);     // 4,194,304 B
    u16*   ybf   = (u16*)(W + 9437184);     // 16,777,216 B (2 slots)
    u16*   h1g   = (u16*)(W + 26214400);    // 16,777,216 B
    float* h_act = (float*)(W + 42991616);  //  2,097,152 B
    float* lse   = (float*)(W + 45088768);  //      4,096 B
    float* topg  = (float*)(W + 45092864);  //      8,192 B
    int*   topi  = (int*)  (W + 45101056);  //      8,192 B
    int*   cnts  = (int*)  (W + 45109248);  //        128 B
    int*   meta  = (int*)  (W + 45109376);  //      8,320 B
    int*   metaF = (int*)  (W + 45117696);  //      8,320 B
    int*   ent   = (int*)  (W + 45126016);  //     65,536 B (end ~45.2 MB)

    convert_kernel<<<4608, 256, 0, stream>>>(w_in, w_o, w1, w2, hw1,
                                             wiBF, woBF, w1BF, w2BF, hw1BF);
    router_kernel<<<1024, 256, 0, stream>>>(z, a, wg, gates_out, lse, topi, topg);
    build_loss_kernel<<<1, 1024, 0, stream>>>(topi, topg, lse, cnts, ent, meta,
                                              metaF, loss_out);
    attn_kernel<<<NTILES, 512, 0, stream>>>(z, a, wiBF, b_in, woBF, b_o,
        l1g, l1b, cnts, meta, ent, h1g);
    ffn_kernel<<<NF_TILES, 512, 0, stream>>>(h1g, w1BF, b1, w2BF, b2,
        l2g, l2b, topg, cnts, metaF, ent, ybf);
    combine_kernel<<<2048, 256, 0, stream>>>(ybf, ybf + 4194304);
    head1_mfma<<<dim3(32, 8), 256, 0, stream>>>(ybf, hw1BF, hb1, h_act);
    head2_kernel<<<1024, 64, 0, stream>>>(h_act, hw2, hb2, r_out);
}

// Round 11
// 320.867 us; speedup vs baseline: 1.0918x; 1.0918x over previous
//
#include <hip/hip_runtime.h>
#include <math.h>

// ---------------------------------------------------------------------------
// CenMoERewardModel. Round 11: expert<->XCD affinity. blockIdx%8 = expert for
// attn/ffn so each XCD's L2 holds only ITS expert's weights (ffn 512KB, attn
// 128KB) instead of all 8 (4MB, thrashed). ffn body reverted to round 9's
// (round 10's PIN/BARX regressed: live-range growth -> 128 VGPR + spill).
// ---------------------------------------------------------------------------

typedef short bf16x8 __attribute__((ext_vector_type(8)));
typedef float f32x4 __attribute__((ext_vector_type(4)));
typedef unsigned short u16;

#define MFMA(a, b, c) __builtin_amdgcn_mfma_f32_16x16x32_bf16((a), (b), (c), 0, 0, 0)

__device__ __forceinline__ u16 f2bf(float f) {
    unsigned int u = __float_as_uint(f);
    unsigned int r = u + 0x7FFFu + ((u >> 16) & 1u);
    return (u16)(r >> 16);
}
__device__ __forceinline__ float bf2f(u16 s) {
    return __uint_as_float(((unsigned int)s) << 16);
}

// ---------------- weight f32 -> bf16 conversion -----------------------------
__global__ __launch_bounds__(256) void convert_kernel(
    const float* __restrict__ wi, const float* __restrict__ wo,
    const float* __restrict__ w1, const float* __restrict__ w2,
    const float* __restrict__ hw1,
    u16* __restrict__ wiB, u16* __restrict__ woB, u16* __restrict__ w1B,
    u16* __restrict__ w2B, u16* __restrict__ hw1B)
{
    int i4 = blockIdx.x * 256 + threadIdx.x;  // 4608*256 = 1,179,648 exact
    int e = i4 * 4;
    const float* s; u16* d; int off;
    if (e < 393216)       { s = wi;  d = wiB;  off = e; }
    else if (e < 524288)  { s = wo;  d = woB;  off = e - 393216; }
    else if (e < 1572864) { s = w1;  d = w1B;  off = e - 524288; }
    else if (e < 2621440) { s = w2;  d = w2B;  off = e - 1572864; }
    else                  { s = hw1; d = hw1B; off = e - 2621440; }
    float4 v = *(const float4*)(s + off);
    ushort4 o;
    o.x = f2bf(v.x); o.y = f2bf(v.y); o.z = f2bf(v.z); o.w = f2bf(v.w);
    *(ushort4*)(d + off) = o;
}

// ---------------- Router (f32 exact) ---------------------------------------
__global__ __launch_bounds__(256) void router_kernel(
    const float* __restrict__ z, const float* __restrict__ a,
    const float* __restrict__ wg,
    float* __restrict__ gates_out, float* __restrict__ lse_ws,
    int* __restrict__ topi, float* __restrict__ topg)
{
    __shared__ float red[256][9];
    const int b = blockIdx.x, t = threadIdx.x;
    float acc[8];
#pragma unroll
    for (int e = 0; e < 8; ++e) acc[e] = 0.f;
#pragma unroll
    for (int i = 0; i < 16; ++i) {
        int f = i * 256 + t;
        int n = f >> 7, d = f & 127;
        float xv = (d < 96) ? z[(b * 32 + n) * 96 + d]
                            : a[(b * 32 + n) * 32 + d - 96];
        const float* wr = wg + f * 8;
#pragma unroll
        for (int e = 0; e < 8; ++e) acc[e] += xv * wr[e];
    }
#pragma unroll
    for (int e = 0; e < 8; ++e) red[t][e] = acc[e];
    __syncthreads();
    for (int s = 128; s; s >>= 1) {
        if (t < s) {
#pragma unroll
            for (int e = 0; e < 8; ++e) red[t][e] += red[t + s][e];
        }
        __syncthreads();
    }
    if (t == 0) {
        float L[8];
#pragma unroll
        for (int e = 0; e < 8; ++e) L[e] = red[0][e];
        int i0 = 0;
#pragma unroll
        for (int e = 1; e < 8; ++e) if (L[e] > L[i0]) i0 = e;
        int i1 = -1; float v1 = -3.0e38f;
#pragma unroll
        for (int e = 0; e < 8; ++e) if (e != i0 && L[e] > v1) { v1 = L[e]; i1 = e; }
        float e1 = expf(v1 - L[i0]);
        float inv = 1.f / (1.f + e1);
        float g0 = inv, g1 = e1 * inv;
#pragma unroll
        for (int e = 0; e < 8; ++e)
            gates_out[b * 8 + e] = (e == i0) ? g0 : ((e == i1) ? g1 : 0.f);
        float m = L[i0];
        float se = 0.f;
#pragma unroll
        for (int e = 0; e < 8; ++e) se += expf(L[e] - m);
        lse_ws[b] = m + logf(se);
        topi[b * 2 + 0] = i0; topi[b * 2 + 1] = i1;
        topg[b * 2 + 0] = g0; topg[b * 2 + 1] = g1;
    }
}

// ---------------- Build entry lists + balance loss --------------------------
// ent[e*2048+i] = token*2+slot ; cnts[e] = entry count.
__global__ __launch_bounds__(1024) void build_loss_kernel(
    const int* __restrict__ topi, const float* __restrict__ topg,
    const float* __restrict__ lse,
    int* __restrict__ cnts, int* __restrict__ ent, float* __restrict__ out_loss)
{
    __shared__ int sc_[8];
    __shared__ float red[9][1024];
    const int t = threadIdx.x;
    if (t < 8) sc_[t] = 0;
    __syncthreads();
    int e0 = topi[t * 2], e1 = topi[t * 2 + 1];
    float g0 = topg[t * 2], g1 = topg[t * 2 + 1];
    int p0 = atomicAdd(&sc_[e0], 1);
    ent[e0 * 2048 + p0] = t * 2;
    int p1 = atomicAdd(&sc_[e1], 1);
    ent[e1 * 2048 + p1] = t * 2 + 1;
#pragma unroll
    for (int e = 0; e < 8; ++e)
        red[e][t] = ((e == e0) ? g0 : 0.f) + ((e == e1) ? g1 : 0.f);
    red[8][t] = lse[t];
    __syncthreads();
    for (int s = 512; s; s >>= 1) {
        if (t < s) {
#pragma unroll
            for (int q = 0; q < 9; ++q) red[q][t] += red[q][t + s];
        }
        __syncthreads();
    }
    if (t == 0) {
        float cvv[2];
        for (int p = 0; p < 2; ++p) {
            float v[8], sum = 0.f;
            for (int e = 0; e < 8; ++e) {
                v[e] = p ? (float)sc_[e] : red[e][0];
                sum += v[e];
            }
            float mean = sum * (1.f / 8.f);
            float var = 0.f;
            for (int e = 0; e < 8; ++e) { float d = v[e] - mean; var += d * d; }
            var *= (1.f / 7.f);
            cvv[p] = var / (mean * mean + 1e-10f);
        }
        out_loss[0] = cvv[0] + cvv[1] + red[8][0] * (1.f / 1024.f);
    }
    __syncthreads();
    if (t < 8) cnts[t] = sc_[t];
}

// ---------------- Attn kernel: M=64, through LN1, writes h1 -----------------
// blockIdx: e = bid & 7 (XCD affinity), tile j = bid >> 3, rows = ent[j*2..].
#define SM_X 0
#define SM_Q 16384
#define SM_K 32768
#define SM_V 49152
#define SM_TOT 65536
#define PS_OFF 0
#define PQ_OFF 1024
#define MU_OFF 2048
#define RS_OFF 2304
#define ATTN_GRID 8192   // 8 experts x up to 1024 pair-tiles

__device__ __forceinline__ int tsw(int row, int col) {   // 256B-row bf16 tile
    return row * 256 + ((col * 2) ^ ((row & 7) << 4));
}
__device__ __forceinline__ int vsw(int row, int col) {   // 128B-row bf16 tile
    return row * 128 + ((col * 2) ^ ((row & 7) << 4));
}

__global__ __launch_bounds__(512, 2) void attn_kernel(
    const float* __restrict__ z, const float* __restrict__ a,
    const u16* __restrict__ wiBF, const float* __restrict__ b_in,
    const u16* __restrict__ woBF, const float* __restrict__ b_out,
    const float* __restrict__ ln1g, const float* __restrict__ ln1b,
    const int* __restrict__ cnts, const int* __restrict__ ent,
    u16* __restrict__ h1g)   // [2048 codes][32][128] bf16
{
    const int e = blockIdx.x & 7, j = blockIdx.x >> 3;
    const int cnt = cnts[e];
    if (j * 2 >= cnt) return;
    const int base = j * 2;

    __shared__ __align__(16) char sm[SM_TOT];
    const int t = threadIdx.x;
    const int w = t >> 6, l = t & 63, l16 = l & 15, lk = l >> 4;
    const int ke = lk * 8;
    const int wr = w >> 2, wc = w & 3;   // 2M x 4N wave grid
    const f32x4 zv = {0.f, 0.f, 0.f, 0.f};

    int bs[2];
#pragma unroll
    for (int i = 0; i < 2; ++i) {
        int gi = base + i;
        int idx = (gi < cnt) ? gi : (cnt - 1);
        bs[i] = ent[e * 2048 + idx];
    }

    // ---- stage X = concat(z,a), bf16 swizzled
#pragma unroll
    for (int i = 0; i < 2; ++i) {
        int cid = i * 512 + t;
        int row = cid >> 4;             // 0..63
        int cb = (cid & 15) * 8;        // 0..120
        int b_ = bs[row >> 5] >> 1;
        int n = row & 31;
        float4 p0, p1;
        if (cb < 96) {
            const float* zp = z + ((size_t)b_ * 32 + n) * 96 + cb;
            p0 = *(const float4*)zp; p1 = *(const float4*)(zp + 4);
        } else {
            const float* ap = a + ((size_t)b_ * 32 + n) * 32 + (cb - 96);
            p0 = *(const float4*)ap; p1 = *(const float4*)(ap + 4);
        }
        bf16x8 pk;
        pk[0] = (short)f2bf(p0.x); pk[1] = (short)f2bf(p0.y);
        pk[2] = (short)f2bf(p0.z); pk[3] = (short)f2bf(p0.w);
        pk[4] = (short)f2bf(p1.x); pk[5] = (short)f2bf(p1.y);
        pk[6] = (short)f2bf(p1.z); pk[7] = (short)f2bf(p1.w);
        *(bf16x8*)(sm + SM_X + tsw(row, cb)) = pk;
    }
    __syncthreads();

    // ---- Phase 1: qkv GEMM  M=64 N=384 K=128
    {
        f32x4 acc[2][6];
#pragma unroll
        for (int mt = 0; mt < 2; ++mt)
#pragma unroll
            for (int q = 0; q < 6; ++q) acc[mt][q] = zv;
#pragma unroll
        for (int ks = 0; ks < 4; ++ks) {
            bf16x8 af[2];
#pragma unroll
            for (int mt = 0; mt < 2; ++mt) {
                int R = wr * 32 + mt * 16 + l16;
                af[mt] = *(const bf16x8*)(sm + SM_X + tsw(R, ks * 32 + ke));
            }
#pragma unroll
            for (int q = 0; q < 6; ++q) {
                int jj = wc * 96 + q * 16 + l16;
                bf16x8 bb = *(const bf16x8*)(wiBF + e * 49152 + jj * 128 + ks * 32 + ke);
#pragma unroll
                for (int mt = 0; mt < 2; ++mt) acc[mt][q] = MFMA(af[mt], bb, acc[mt][q]);
            }
        }
#pragma unroll
        for (int q = 0; q < 6; ++q) {
            int C = wc * 96 + q * 16 + l16;
            float bj = b_in[e * 384 + C];
#pragma unroll
            for (int mt = 0; mt < 2; ++mt)
#pragma unroll
                for (int i = 0; i < 4; ++i) {
                    int R = wr * 32 + mt * 16 + lk * 4 + i;
                    u16 val = f2bf(acc[mt][q][i] + bj);
                    if (C < 128) {
                        *(u16*)(sm + SM_Q + tsw(R, C)) = val;
                    } else if (C < 256) {
                        *(u16*)(sm + SM_K + tsw(R, C - 128)) = val;
                    } else {
                        *(u16*)(sm + SM_V + vsw(C - 256, R)) = val;  // VT[d][key]
                    }
                }
        }
    }
    __syncthreads();

    // ---- Phase 2: attention; wave w -> (tok = w>>2, head = w&3)
    {
        const int tok = w >> 2, hb = (w & 3) * 32;
        const float scale = 0.17677669529663687f;  // 1/sqrt(32)
        bf16x8 qa[2], kf[2];
#pragma unroll
        for (int mt = 0; mt < 2; ++mt) {
            int R = tok * 32 + mt * 16 + l16;
            qa[mt] = *(const bf16x8*)(sm + SM_Q + tsw(R, hb + ke));
            kf[mt] = *(const bf16x8*)(sm + SM_K + tsw(R, hb + ke));
        }
        f32x4 sc[2][2];
        sc[0][0] = MFMA(qa[0], kf[0], zv); sc[0][1] = MFMA(qa[0], kf[1], zv);
        sc[1][0] = MFMA(qa[1], kf[0], zv); sc[1][1] = MFMA(qa[1], kf[1], zv);
#pragma unroll
        for (int mt = 0; mt < 2; ++mt)
#pragma unroll
            for (int i = 0; i < 4; ++i) {
                float v0 = sc[mt][0][i] * scale, v1 = sc[mt][1][i] * scale;
                float m = fmaxf(v0, v1);
                m = fmaxf(m, __shfl_xor(m, 1)); m = fmaxf(m, __shfl_xor(m, 2));
                m = fmaxf(m, __shfl_xor(m, 4)); m = fmaxf(m, __shfl_xor(m, 8));
                float e0 = __expf(v0 - m), e1 = __expf(v1 - m);
                float ssum = e0 + e1;
                ssum += __shfl_xor(ssum, 1); ssum += __shfl_xor(ssum, 2);
                ssum += __shfl_xor(ssum, 4); ssum += __shfl_xor(ssum, 8);
                float inv = 1.f / ssum;
                int row = mt * 16 + lk * 4 + i;
                char* pb = sm + SM_X + w * 2048 + row * 64;
                int sw = (row & 3) << 4;
                *(u16*)(pb + ((l16 * 2) ^ sw)) = f2bf(e0 * inv);
                *(u16*)(pb + (((16 + l16) * 2) ^ sw)) = f2bf(e1 * inv);
            }
        bf16x8 pa[2];
#pragma unroll
        for (int mt = 0; mt < 2; ++mt) {
            int row = mt * 16 + l16;
            pa[mt] = *(const bf16x8*)(sm + SM_X + w * 2048 + row * 64 +
                                      ((ke * 2) ^ ((row & 3) << 4)));
        }
        f32x4 o[2][2];
#pragma unroll
        for (int nt = 0; nt < 2; ++nt) {
            int rv = hb + nt * 16 + l16;  // VT row = v column
            bf16x8 vb = *(const bf16x8*)(sm + SM_V + vsw(rv, tok * 32 + ke));
            o[0][nt] = MFMA(pa[0], vb, zv);
            o[1][nt] = MFMA(pa[1], vb, zv);
        }
#pragma unroll
        for (int mt = 0; mt < 2; ++mt)
#pragma unroll
            for (int nt = 0; nt < 2; ++nt)
#pragma unroll
                for (int i = 0; i < 4; ++i) {
                    int R = tok * 32 + mt * 16 + lk * 4 + i;
                    int C = hb + nt * 16 + l16;
                    *(u16*)(sm + SM_Q + tsw(R, C)) = f2bf(o[mt][nt][i]);
                }
    }
    __syncthreads();

    // ---- Phase 3: proj GEMM + residual(global f32) + LN1 stats
    {
        f32x4 pr[2][2];
        pr[0][0] = zv; pr[0][1] = zv; pr[1][0] = zv; pr[1][1] = zv;
#pragma unroll
        for (int ks = 0; ks < 4; ++ks) {
            bf16x8 af[2];
#pragma unroll
            for (int mt = 0; mt < 2; ++mt) {
                int R = wr * 32 + mt * 16 + l16;
                af[mt] = *(const bf16x8*)(sm + SM_Q + tsw(R, ks * 32 + ke));
            }
#pragma unroll
            for (int nt = 0; nt < 2; ++nt) {
                int jj = wc * 32 + nt * 16 + l16;
                bf16x8 bb = *(const bf16x8*)(woBF + e * 16384 + jj * 128 + ks * 32 + ke);
                pr[0][nt] = MFMA(af[0], bb, pr[0][nt]);
                pr[1][nt] = MFMA(af[1], bb, pr[1][nt]);
            }
        }
        int C0 = wc * 32 + l16, C1 = C0 + 16;
        float bo0 = b_out[e * 128 + C0];
        float bo1 = b_out[e * 128 + C1];
        int b_ = bs[wr] >> 1;
#pragma unroll
        for (int mt = 0; mt < 2; ++mt)
#pragma unroll
            for (int i = 0; i < 4; ++i) {
                int R = wr * 32 + mt * 16 + lk * 4 + i;
                int n = R & 31;
                float x0 = (C0 < 96) ? z[((size_t)b_ * 32 + n) * 96 + C0]
                                     : a[((size_t)b_ * 32 + n) * 32 + C0 - 96];
                float x1 = (C1 < 96) ? z[((size_t)b_ * 32 + n) * 96 + C1]
                                     : a[((size_t)b_ * 32 + n) * 32 + C1 - 96];
                float u0 = pr[mt][0][i] + bo0 + x0;
                float u1v = pr[mt][1][i] + bo1 + x1;
                *(u16*)(sm + SM_K + tsw(R, C0)) = f2bf(u0);
                *(u16*)(sm + SM_K + tsw(R, C1)) = f2bf(u1v);
                float s = u0 + u1v;
                float q = u0 * u0 + u1v * u1v;
                s += __shfl_xor(s, 1); q += __shfl_xor(q, 1);
                s += __shfl_xor(s, 2); q += __shfl_xor(q, 2);
                s += __shfl_xor(s, 4); q += __shfl_xor(q, 4);
                s += __shfl_xor(s, 8); q += __shfl_xor(q, 8);
                if (l16 == 0) {
                    *(float*)(sm + SM_X + PS_OFF + (R * 4 + wc) * 4) = s;
                    *(float*)(sm + SM_X + PQ_OFF + (R * 4 + wc) * 4) = q;
                }
            }
    }
    __syncthreads();
    if (t < 64) {
        float s = 0.f, q = 0.f;
#pragma unroll
        for (int c = 0; c < 4; ++c) {
            s += *(const float*)(sm + SM_X + PS_OFF + (t * 4 + c) * 4);
            q += *(const float*)(sm + SM_X + PQ_OFF + (t * 4 + c) * 4);
        }
        float mu = s * (1.f / 128.f);
        float var = q * (1.f / 128.f) - mu * mu;
        *(float*)(sm + SM_X + MU_OFF + t * 4) = mu;
        *(float*)(sm + SM_X + RS_OFF + t * 4) = rsqrtf(var + 1e-5f);
    }
    __syncthreads();
    {   // LN1 apply in place over SM_K
        int r_ = t >> 3, c0 = (t & 7) * 16;
        float mu_ = *(const float*)(sm + SM_X + MU_OFF + r_ * 4);
        float rs_ = *(const float*)(sm + SM_X + RS_OFF + r_ * 4);
#pragma unroll
        for (int j4 = 0; j4 < 2; ++j4) {
            int cb = c0 + j4 * 8;
            bf16x8* p = (bf16x8*)(sm + SM_K + tsw(r_, cb));
            bf16x8 vch = *p;
#pragma unroll
            for (int jj = 0; jj < 8; ++jj) {
                int c = cb + jj;
                float f = (bf2f((u16)vch[jj]) - mu_) * rs_ * ln1g[e * 128 + c] + ln1b[e * 128 + c];
                vch[jj] = (short)f2bf(f);
            }
            *p = vch;
        }
    }
    __syncthreads();
    // ---- write h1 to global (duplicate entries write identical bytes: benign)
#pragma unroll
    for (int i = 0; i < 2; ++i) {
        int cid = i * 512 + t;
        int r_ = cid >> 4, cb = (cid & 15) * 8;
        int code = bs[r_ >> 5];
        u16* dst = h1g + (size_t)code * 4096 + (r_ & 31) * 128 + cb;
        *(bf16x8*)dst = *(const bf16x8*)(sm + SM_K + tsw(r_, cb));
    }
}

// ---------------- FFN kernel: M=128 grouped GEMM per expert -----------------
// blockIdx: e = bid & 7 (XCD affinity), tile j = bid >> 3 (4 entries each).
#define FH 0
#define FF 32768
#define FPS 65536
#define FPQ 67584
#define FMU 69632
#define FRS 70144
#define F_TOT 70656
#define FFN_GRID 4096   // 8 experts x up to 512 quad-tiles

__global__ __launch_bounds__(512, 2) void ffn_kernel(
    const u16* __restrict__ h1g,
    const u16* __restrict__ w1BF, const float* __restrict__ b1,
    const u16* __restrict__ w2BF, const float* __restrict__ b2,
    const float* __restrict__ ln2g, const float* __restrict__ ln2b,
    const float* __restrict__ topg, const int* __restrict__ cnts,
    const int* __restrict__ ent,
    u16* __restrict__ ybf)   // [2][1024][4096]
{
    const int e = blockIdx.x & 7, jt = blockIdx.x >> 3;
    const int cnt = cnts[e];
    if (jt * 4 >= cnt) return;
    const int base = jt * 4;

    __shared__ __align__(16) char sm[F_TOT];
    const int t = threadIdx.x;
    const int w = t >> 6, l = t & 63, l16 = l & 15, lk = l >> 4;
    const int ke = lk * 8;
    const int wr = w >> 2, wc = w & 3;   // 2M x 4N
    const f32x4 zv = {0.f, 0.f, 0.f, 0.f};

    int code4[4]; float gg4[4];
#pragma unroll
    for (int i = 0; i < 4; ++i) {
        int gi = base + i;
        int idx = (gi < cnt) ? gi : (cnt - 1);
        code4[i] = ent[e * 2048 + idx];
        gg4[i] = topg[code4[i]];
    }

    // ---- stage H (LN1 output) from global: 128 rows x 128 cols
#pragma unroll
    for (int it = 0; it < 4; ++it) {
        int cid = it * 512 + t;
        int row = cid >> 4, cb = (cid & 15) * 8;
        int code = code4[row >> 5];
        *(bf16x8*)(sm + FH + tsw(row, cb)) =
            *(const bf16x8*)(h1g + (size_t)code * 4096 + (row & 31) * 128 + cb);
    }
    __syncthreads();

    f32x4 facc[4][2];
#pragma unroll
    for (int mt = 0; mt < 4; ++mt) { facc[mt][0] = zv; facc[mt][1] = zv; }

    for (int c = 0; c < 8; ++c) {
        // GEMM1: a1 = H @ W1_chunk^T  (M=128 N=128 K=128; 32 MFMA/wave)
        f32x4 a1[4][2];
#pragma unroll
        for (int mt = 0; mt < 4; ++mt) { a1[mt][0] = zv; a1[mt][1] = zv; }
#pragma unroll
        for (int ks = 0; ks < 4; ++ks) {
            bf16x8 af[4];
#pragma unroll
            for (int mt = 0; mt < 4; ++mt) {
                int R = wr * 64 + mt * 16 + l16;
                af[mt] = *(const bf16x8*)(sm + FH + tsw(R, ks * 32 + ke));
            }
#pragma unroll
            for (int nt = 0; nt < 2; ++nt) {
                int jj = c * 128 + wc * 32 + nt * 16 + l16;
                bf16x8 bb = *(const bf16x8*)(w1BF + e * 131072 + jj * 128 + ks * 32 + ke);
#pragma unroll
                for (int mt = 0; mt < 4; ++mt) a1[mt][nt] = MFMA(af[mt], bb, a1[mt][nt]);
            }
        }
        __syncthreads();   // prev chunk's F reads (GEMM2) complete
#pragma unroll
        for (int nt = 0; nt < 2; ++nt) {
            int C = wc * 32 + nt * 16 + l16;
            float bv = b1[e * 1024 + c * 128 + C];
#pragma unroll
            for (int mt = 0; mt < 4; ++mt)
#pragma unroll
                for (int i = 0; i < 4; ++i) {
                    int R = wr * 64 + mt * 16 + lk * 4 + i;
                    *(u16*)(sm + FF + tsw(R, C)) = f2bf(fmaxf(a1[mt][nt][i] + bv, 0.f));
                }
        }
        __syncthreads();   // F ready
        // GEMM2: facc += F @ W2_chunk^T  (32 MFMA/wave)
#pragma unroll
        for (int ks = 0; ks < 4; ++ks) {
            bf16x8 af[4];
#pragma unroll
            for (int mt = 0; mt < 4; ++mt) {
                int R = wr * 64 + mt * 16 + l16;
                af[mt] = *(const bf16x8*)(sm + FF + tsw(R, ks * 32 + ke));
            }
#pragma unroll
            for (int nt = 0; nt < 2; ++nt) {
                int jj = wc * 32 + nt * 16 + l16;
                bf16x8 bb = *(const bf16x8*)(w2BF + e * 131072 + jj * 1024 +
                                             c * 128 + ks * 32 + ke);
#pragma unroll
                for (int mt = 0; mt < 4; ++mt) facc[mt][nt] = MFMA(af[mt], bb, facc[mt][nt]);
            }
        }
    }
    __syncthreads();   // last GEMM2's F reads done before u2 overwrites F

    // ---- epilogue: u2 = h1 + facc + b2 -> F (bf16); per-row partial stats
    {
        int C0 = wc * 32 + l16, C1 = C0 + 16;
        float b20 = b2[e * 128 + C0];
        float b21 = b2[e * 128 + C1];
#pragma unroll
        for (int mt = 0; mt < 4; ++mt)
#pragma unroll
            for (int i = 0; i < 4; ++i) {
                int R = wr * 64 + mt * 16 + lk * 4 + i;
                float h0 = bf2f(*(const u16*)(sm + FH + tsw(R, C0)));
                float h1v = bf2f(*(const u16*)(sm + FH + tsw(R, C1)));
                float u0 = facc[mt][0][i] + b20 + h0;
                float u1v = facc[mt][1][i] + b21 + h1v;
                *(u16*)(sm + FF + tsw(R, C0)) = f2bf(u0);
                *(u16*)(sm + FF + tsw(R, C1)) = f2bf(u1v);
                float s = u0 + u1v;
                float q = u0 * u0 + u1v * u1v;
                s += __shfl_xor(s, 1); q += __shfl_xor(q, 1);
                s += __shfl_xor(s, 2); q += __shfl_xor(q, 2);
                s += __shfl_xor(s, 4); q += __shfl_xor(q, 4);
                s += __shfl_xor(s, 8); q += __shfl_xor(q, 8);
                if (l16 == 0) {
                    *(float*)(sm + FPS + (R * 4 + wc) * 4) = s;
                    *(float*)(sm + FPQ + (R * 4 + wc) * 4) = q;
                }
            }
    }
    __syncthreads();
    if (t < 128) {
        float s = 0.f, q = 0.f;
#pragma unroll
        for (int c = 0; c < 4; ++c) {
            s += *(const float*)(sm + FPS + (t * 4 + c) * 4);
            q += *(const float*)(sm + FPQ + (t * 4 + c) * 4);
        }
        float mu = s * (1.f / 128.f);
        float var = q * (1.f / 128.f) - mu * mu;
        *(float*)(sm + FMU + t * 4) = mu;
        *(float*)(sm + FRS + t * 4) = rsqrtf(var + 1e-5f);
    }
    __syncthreads();
    // ---- LN2 apply + gate + write (duplicates write identical bytes)
#pragma unroll
    for (int it = 0; it < 4; ++it) {
        int cid = it * 512 + t;
        int row = cid >> 4, cb = (cid & 15) * 8;
        float mu = *(const float*)(sm + FMU + row * 4);
        float rs = *(const float*)(sm + FRS + row * 4);
        int ei = row >> 5;
        float gm = gg4[ei];
        int code = code4[ei];
        int tok = code >> 1, slot = code & 1;
        bf16x8 v = *(const bf16x8*)(sm + FF + tsw(row, cb));
        bf16x8 o;
#pragma unroll
        for (int jj = 0; jj < 8; ++jj) {
            int cc = cb + jj;
            float f = (bf2f((u16)v[jj]) - mu) * rs * ln2g[e * 128 + cc] + ln2b[e * 128 + cc];
            o[jj] = (short)f2bf(gm * f);
        }
        *(bf16x8*)(ybf + (size_t)(slot * 1024 + tok) * 4096 + (row & 31) * 128 + cb) = o;
    }
}

// ---------------- Combine: y = slot0 + slot1 (into slot0) ------------------
__global__ __launch_bounds__(256) void combine_kernel(
    u16* __restrict__ y0, const u16* __restrict__ y1)
{
    int i = (blockIdx.x * 256 + threadIdx.x) * 8;
    bf16x8 a = *(const bf16x8*)(y0 + i);
    bf16x8 b = *(const bf16x8*)(y1 + i);
    bf16x8 o;
#pragma unroll
    for (int j = 0; j < 8; ++j)
        o[j] = (short)f2bf(bf2f((u16)a[j]) + bf2f((u16)b[j]));
    *(bf16x8*)(y0 + i) = o;
}

// ---------------- Head1: h_act = relu(y @ hw1^T + hb1), bf16 MFMA -----------
__global__ __launch_bounds__(256) void head1_mfma(
    const u16* __restrict__ y_bf, const u16* __restrict__ hw1BF,
    const float* __restrict__ hb1, float* __restrict__ h_act)
{
    const int t = threadIdx.x, w = t >> 6, l = t & 63, l16 = l & 15, lk = l >> 4;
    const int ke = lk * 8;
    const int mb = blockIdx.x * 32, cb = blockIdx.y * 64 + w * 16;
    const f32x4 zv = {0.f, 0.f, 0.f, 0.f};
    f32x4 acc[2]; acc[0] = zv; acc[1] = zv;
    const u16* arow0 = y_bf + (size_t)(mb + l16) * 4096;
    const u16* arow1 = y_bf + (size_t)(mb + 16 + l16) * 4096;
    const u16* brow  = hw1BF + (size_t)(cb + l16) * 4096;
    for (int k0 = 0; k0 < 4096; k0 += 32) {
        bf16x8 a0 = *(const bf16x8*)(arow0 + k0 + ke);
        bf16x8 a1 = *(const bf16x8*)(arow1 + k0 + ke);
        bf16x8 bb = *(const bf16x8*)(brow + k0 + ke);
        acc[0] = MFMA(a0, bb, acc[0]);
        acc[1] = MFMA(a1, bb, acc[1]);
    }
    int col = cb + l16;
    float bv = hb1[col];
#pragma unroll
    for (int mt = 0; mt < 2; ++mt)
#pragma unroll
        for (int i = 0; i < 4; ++i) {
            int row = mb + mt * 16 + lk * 4 + i;
            h_act[(size_t)row * 512 + col] = fmaxf(acc[mt][i] + bv, 0.f);
        }
}

// ---------------- Head2 -----------------------------------------------------
__global__ __launch_bounds__(64) void head2_kernel(
    const float* __restrict__ h_act, const float* __restrict__ w2,
    const float* __restrict__ b2, float* __restrict__ r)
{
    const int b = blockIdx.x, t = threadIdx.x;
    float a0 = 0.f, a1 = 0.f, a2 = 0.f, a3 = 0.f;
    for (int h = t; h < 512; h += 64) {
        float hv = h_act[b * 512 + h];
        a0 += hv * w2[h];
        a1 += hv * w2[512 + h];
        a2 += hv * w2[1024 + h];
        a3 += hv * w2[1536 + h];
    }
#pragma unroll
    for (int off = 32; off; off >>= 1) {
        a0 += __shfl_down(a0, off);
        a1 += __shfl_down(a1, off);
        a2 += __shfl_down(a2, off);
        a3 += __shfl_down(a3, off);
    }
    if (t == 0) {
        r[b * 4 + 0] = a0 + b2[0];
        r[b * 4 + 1] = a1 + b2[1];
        r[b * 4 + 2] = a2 + b2[2];
        r[b * 4 + 3] = a3 + b2[3];
    }
}

// ---------------------------------------------------------------------------
extern "C" void kernel_launch(void* const* d_in, const int* in_sizes, int n_in,
                              void* d_out, int out_size, void* d_ws, size_t ws_size,
                              hipStream_t stream) {
    const float* z    = (const float*)d_in[0];
    const float* a    = (const float*)d_in[1];
    const float* wg   = (const float*)d_in[2];
    const float* w_in = (const float*)d_in[3];
    const float* b_in = (const float*)d_in[4];
    const float* w_o  = (const float*)d_in[5];
    const float* b_o  = (const float*)d_in[6];
    const float* l1g  = (const float*)d_in[7];
    const float* l1b  = (const float*)d_in[8];
    const float* w1   = (const float*)d_in[9];
    const float* b1   = (const float*)d_in[10];
    const float* w2   = (const float*)d_in[11];
    const float* b2   = (const float*)d_in[12];
    const float* l2g  = (const float*)d_in[13];
    const float* l2b  = (const float*)d_in[14];
    const float* hw1  = (const float*)d_in[15];
    const float* hb1  = (const float*)d_in[16];
    const float* hw2  = (const float*)d_in[17];
    const float* hb2  = (const float*)d_in[18];

    float* out = (float*)d_out;
    float* r_out     = out;          // 4096
    float* gates_out = out + 4096;   // 8192
    float* loss_out  = out + 12288;  // 1

    char* W = (char*)d_ws;
    u16*   wiBF  = (u16*)(W + 0);           //   786,432 B
    u16*   woBF  = (u16*)(W + 786432);      //   262,144 B
    u16*   w1BF  = (u16*)(W + 1048576);     // 2,097,152 B
    u16*   w2BF  = (u16*)(W + 3145728);     // 2,097,152 B
    u16*   hw1BF = (u16*)(W + 5242880);     // 4,194,304 B
    u16*   ybf   = (u16*)(W + 9437184);     // 16,777,216 B (2 slots)
    u16*   h1g   = (u16*)(W + 26214400);    // 16,777,216 B
    float* h_act = (float*)(W + 42991616);  //  2,097,152 B
    float* lse   = (float*)(W + 45088768);  //      4,096 B
    float* topg  = (float*)(W + 45092864);  //      8,192 B
    int*   topi  = (int*)  (W + 45101056);  //      8,192 B
    int*   cnts  = (int*)  (W + 45109248);  //        128 B
    int*   ent   = (int*)  (W + 45109376);  //     65,536 B (end ~45.2 MB)

    convert_kernel<<<4608, 256, 0, stream>>>(w_in, w_o, w1, w2, hw1,
                                             wiBF, woBF, w1BF, w2BF, hw1BF);
    router_kernel<<<1024, 256, 0, stream>>>(z, a, wg, gates_out, lse, topi, topg);
    build_loss_kernel<<<1, 1024, 0, stream>>>(topi, topg, lse, cnts, ent, loss_out);
    attn_kernel<<<ATTN_GRID, 512, 0, stream>>>(z, a, wiBF, b_in, woBF, b_o,
        l1g, l1b, cnts, ent, h1g);
    ffn_kernel<<<FFN_GRID, 512, 0, stream>>>(h1g, w1BF, b1, w2BF, b2,
        l2g, l2b, topg, cnts, ent, ybf);
    combine_kernel<<<2048, 256, 0, stream>>>(ybf, ybf + 4194304);
    head1_mfma<<<dim3(32, 8), 256, 0, stream>>>(ybf, hw1BF, hb1, h_act);
    head2_kernel<<<1024, 64, 0, stream>>>(h_act, hw2, hb2, r_out);
}